// Round 1
// baseline (2817.453 us; speedup 1.0000x reference)
//
#include <hip/hip_runtime.h>
#include <hip/hip_bf16.h>
#include <float.h>
#include <math.h>

// ---------------- problem constants (fixed by reference) ----------------
constexpr int N_PER = 5000, NB = 10, E_PER = 40000;
constexpr int NN = N_PER * NB;   // 50000 nodes
constexpr int E0 = E_PER * NB;   // 400000 edges (without self loops)
constexpr int ET = E0 + NN;      // 450000 edges incl. self loops
constexpr int DIN = 1024, DH = 64, HEADS = 8, F1 = 512;  // F1 = HEADS*DH
constexpr int KSEL = 2500;       // ceil(0.5 * N_PER)

#define DEV __device__ __forceinline__

DEV float wave_sum(float v) {
#pragma unroll
  for (int off = 32; off; off >>= 1) v += __shfl_xor(v, off);
  return v;
}

// ---------------- CSR build ----------------
__global__ void deg_kernel(const int* __restrict__ dstArr, int* __restrict__ deg) {
  int e = blockIdx.x * 256 + threadIdx.x;
  if (e >= ET) return;
  int d = (e < E0) ? dstArr[e] : (e - E0);
  atomicAdd(&deg[d], 1);
}

__global__ __launch_bounds__(1024) void scan_kernel(const int* __restrict__ deg,
                                                    int* __restrict__ rowptr) {
  __shared__ int s[1024];
  __shared__ int carry;
  const int tid = threadIdx.x;
  if (tid == 0) { carry = 0; rowptr[0] = 0; }
  __syncthreads();
  for (int base = 0; base < NN; base += 1024) {
    int v = (base + tid < NN) ? deg[base + tid] : 0;
    s[tid] = v;
    __syncthreads();
    for (int off = 1; off < 1024; off <<= 1) {
      int add = (tid >= off) ? s[tid - off] : 0;
      __syncthreads();
      s[tid] += add;
      __syncthreads();
    }
    if (base + tid < NN) rowptr[base + tid + 1] = carry + s[tid];
    __syncthreads();
    if (tid == 0) carry += s[1023];
    __syncthreads();
  }
}

__global__ void fill_kernel(const int* __restrict__ dstArr, const int* __restrict__ rowptr,
                            int* __restrict__ cnt, int* __restrict__ eid) {
  int e = blockIdx.x * 256 + threadIdx.x;
  if (e >= ET) return;
  int d = (e < E0) ? dstArr[e] : (e - E0);
  int pos = rowptr[d] + atomicAdd(&cnt[d], 1);
  eid[pos] = e;
}

// ---------------- dual-output f32 GEMM: Cl = A@Bl, Cr = A@Br ----------------
// A [M,Kd] row-major, B [Kd,Nc] row-major. BM=BN=64, BK=16, 256 threads.
__global__ __launch_bounds__(256) void dual_gemm_kernel(
    const float* __restrict__ A, const float* __restrict__ Bl, const float* __restrict__ Br,
    float* __restrict__ Cl, float* __restrict__ Cr, int M, int Kd, int Nc) {
  constexpr int BM = 64, BN = 64, BK = 16;
  __shared__ float As[BK][BM];
  __shared__ float Bsl[BK][BN];
  __shared__ float Bsr[BK][BN];
  const int tid = threadIdx.x;
  const int row0 = blockIdx.x * BM;
  const int col0 = blockIdx.y * BN;
  const int la_m = tid >> 2, la_k = (tid & 3) << 2;    // A loader: 64 rows x 4 k (float4)
  const int lb_k = tid >> 4, lb_n = (tid & 15) << 2;   // B loader: 16 k x 16 float4
  const int ty = tid >> 4, tx = tid & 15;
  float accl[4][4] = {{0.f}}, accr[4][4] = {{0.f}};
  for (int kt = 0; kt < Kd; kt += BK) {
    float4 av = make_float4(0.f, 0.f, 0.f, 0.f);
    const int ar = row0 + la_m;
    if (ar < M) av = *(const float4*)(A + (size_t)ar * Kd + kt + la_k);
    const float4 blv = *(const float4*)(Bl + (size_t)(kt + lb_k) * Nc + col0 + lb_n);
    const float4 brv = *(const float4*)(Br + (size_t)(kt + lb_k) * Nc + col0 + lb_n);
    __syncthreads();
    As[la_k + 0][la_m] = av.x;
    As[la_k + 1][la_m] = av.y;
    As[la_k + 2][la_m] = av.z;
    As[la_k + 3][la_m] = av.w;
    *(float4*)(&Bsl[lb_k][lb_n]) = blv;
    *(float4*)(&Bsr[lb_k][lb_n]) = brv;
    __syncthreads();
#pragma unroll
    for (int k = 0; k < BK; ++k) {
      const float4 a = *(const float4*)(&As[k][ty << 2]);
      const float4 bl = *(const float4*)(&Bsl[k][tx << 2]);
      const float4 br = *(const float4*)(&Bsr[k][tx << 2]);
      const float aa[4] = {a.x, a.y, a.z, a.w};
      const float bb[4] = {bl.x, bl.y, bl.z, bl.w};
      const float cc[4] = {br.x, br.y, br.z, br.w};
#pragma unroll
      for (int i = 0; i < 4; ++i)
#pragma unroll
        for (int j = 0; j < 4; ++j) {
          accl[i][j] = fmaf(aa[i], bb[j], accl[i][j]);
          accr[i][j] = fmaf(aa[i], cc[j], accr[i][j]);
        }
    }
  }
#pragma unroll
  for (int i = 0; i < 4; ++i) {
    const int row = row0 + (ty << 2) + i;
    if (row < M) {
      float4 vl = make_float4(accl[i][0], accl[i][1], accl[i][2], accl[i][3]);
      float4 vr = make_float4(accr[i][0], accr[i][1], accr[i][2], accr[i][3]);
      *(float4*)(Cl + (size_t)row * Nc + col0 + (tx << 2)) = vl;
      *(float4*)(Cr + (size_t)row * Nc + col0 + (tx << 2)) = vr;
    }
  }
}

// ---------------- layer-1 edge logits: wave per edge ----------------
__global__ __launch_bounds__(256) void edge1_kernel(
    const float* __restrict__ xl, const float* __restrict__ xr,
    const int* __restrict__ srcArr, const int* __restrict__ dstArr,
    const float* __restrict__ a1, float* __restrict__ logit) {
  const int wid = ((blockIdx.x * 256) + threadIdx.x) >> 6;
  const int lane = threadIdx.x & 63;
  if (wid >= ET) return;
  const int e = wid;
  const int s = (e < E0) ? srcArr[e] : (e - E0);
  const int d = (e < E0) ? dstArr[e] : (e - E0);
  const float* pl = xl + (size_t)s * F1;
  const float* pr = xr + (size_t)d * F1;
  float part[HEADS];
#pragma unroll
  for (int h = 0; h < HEADS; ++h) {
    float v = pl[h * 64 + lane] + pr[h * 64 + lane];
    v = (v >= 0.f) ? v : 0.2f * v;   // leaky_relu(., 0.2)
    part[h] = v * a1[h * 64 + lane];
  }
#pragma unroll
  for (int off = 32; off; off >>= 1) {
#pragma unroll
    for (int h = 0; h < HEADS; ++h) part[h] += __shfl_xor(part[h], off);
  }
  if (lane == 0) {
    *(float4*)(logit + (size_t)e * 8)     = make_float4(part[0], part[1], part[2], part[3]);
    *(float4*)(logit + (size_t)e * 8 + 4) = make_float4(part[4], part[5], part[6], part[7]);
  }
}

// ---------------- layer-1 per-node softmax + aggregation + ELU ----------------
__global__ __launch_bounds__(512) void node1_kernel(
    const float* __restrict__ xl1, const float* __restrict__ logit1,
    const int* __restrict__ srcArr, const int* __restrict__ rowptr,
    const int* __restrict__ eid, const float* __restrict__ b1, float* __restrict__ h1) {
  const int n = blockIdx.x;
  const int tid = threadIdx.x;           // 512 = 8 waves
  const int h = tid >> 6, lane = tid & 63;
  const int base = rowptr[n], deg = rowptr[n + 1] - base;
  __shared__ float sm_m[HEADS], sm_inv[HEADS];
  // phase A: wave h -> (max, sum exp) over incoming edges for head h
  float m = -FLT_MAX, s = 0.f;
  for (int i = lane; i < deg; i += 64) {
    const int e = eid[base + i];
    const float lg = logit1[(size_t)e * 8 + h];
    if (lg > m) { s = s * __expf(m - lg) + 1.f; m = lg; }
    else s += __expf(lg - m);
  }
#pragma unroll
  for (int off = 32; off; off >>= 1) {
    const float m2 = __shfl_xor(m, off), s2 = __shfl_xor(s, off);
    const float M = fmaxf(m, m2);
    s = s * __expf(m - M) + s2 * __expf(m2 - M);
    m = M;
  }
  if (lane == 0) { sm_m[h] = m; sm_inv[h] = 1.f / (s + 1e-16f); }
  __syncthreads();
  const float mh = sm_m[h], inv = sm_inv[h];
  // phase B: thread owns channel tid = h*64+c
  float acc = 0.f;
  for (int i = 0; i < deg; ++i) {
    const int e = eid[base + i];
    const int src = (e < E0) ? srcArr[e] : (e - E0);
    const float lg = logit1[(size_t)e * 8 + h];
    const float wgt = __expf(lg - mh) * inv;
    acc = fmaf(wgt, xl1[(size_t)src * F1 + tid], acc);
  }
  const float v = acc + b1[tid];
  h1[(size_t)n * F1 + tid] = (v > 0.f) ? v : expm1f(v);  // ELU(alpha=1)
}

// ---------------- layer-2 edge logits ----------------
__global__ __launch_bounds__(256) void edge2_kernel(
    const float* __restrict__ xl, const float* __restrict__ xr,
    const int* __restrict__ srcArr, const int* __restrict__ dstArr,
    const float* __restrict__ a2, float* __restrict__ logit) {
  const int wid = ((blockIdx.x * 256) + threadIdx.x) >> 6;
  const int lane = threadIdx.x & 63;
  if (wid >= ET) return;
  const int e = wid;
  const int s = (e < E0) ? srcArr[e] : (e - E0);
  const int d = (e < E0) ? dstArr[e] : (e - E0);
  float v = xl[(size_t)s * DH + lane] + xr[(size_t)d * DH + lane];
  v = (v >= 0.f) ? v : 0.2f * v;
  v *= a2[lane];
  v = wave_sum(v);
  if (lane == 0) logit[e] = v;
}

// ---------------- layer-2 node: softmax agg + SELU + xw/dinv ----------------
__global__ __launch_bounds__(64) void node2_kernel(
    const float* __restrict__ xl2, const float* __restrict__ logit2,
    const int* __restrict__ srcArr, const int* __restrict__ rowptr,
    const int* __restrict__ eid, const float* __restrict__ b2, const float* __restrict__ Wp,
    float* __restrict__ h2, float* __restrict__ q, float* __restrict__ dinvArr) {
  const int n = blockIdx.x, lane = threadIdx.x;  // 64 threads = 1 wave
  const int base = rowptr[n], deg = rowptr[n + 1] - base;
  float m = -FLT_MAX, s = 0.f;
  for (int i = lane; i < deg; i += 64) {
    const float lg = logit2[eid[base + i]];
    if (lg > m) { s = s * __expf(m - lg) + 1.f; m = lg; }
    else s += __expf(lg - m);
  }
#pragma unroll
  for (int off = 32; off; off >>= 1) {
    const float m2 = __shfl_xor(m, off), s2 = __shfl_xor(s, off);
    const float M = fmaxf(m, m2);
    s = s * __expf(m - M) + s2 * __expf(m2 - M);
    m = M;
  }
  const float inv = 1.f / (s + 1e-16f);
  float acc = 0.f;
  for (int i = 0; i < deg; ++i) {
    const int e = eid[base + i];
    const int src = (e < E0) ? srcArr[e] : (e - E0);
    const float wgt = __expf(logit2[e] - m) * inv;
    acc = fmaf(wgt, xl2[(size_t)src * DH + lane], acc);
  }
  const float v = acc + b2[lane];
  constexpr float SC = 1.0507009873554804934f, AL = 1.6732632423543772848f;
  const float hv = (v > 0.f) ? SC * v : SC * AL * expm1f(v);
  h2[(size_t)n * DH + lane] = hv;
  float p = wave_sum(hv * Wp[lane]);   // xw[n]
  if (lane == 0) {
    const float di = 1.f / sqrtf((float)deg);  // deg >= 1 (self loop)
    q[n] = di * p;
    dinvArr[n] = di;
  }
}

// ---------------- GCN score ----------------
__global__ void score_kernel(const int* __restrict__ srcArr, const int* __restrict__ rowptr,
                             const int* __restrict__ eid, const float* __restrict__ q,
                             const float* __restrict__ dinvArr, const float* __restrict__ bp,
                             float* __restrict__ score) {
  const int n = blockIdx.x * 256 + threadIdx.x;
  if (n >= NN) return;
  const int base = rowptr[n], deg = rowptr[n + 1] - base;
  float s = 0.f;
  for (int i = 0; i < deg; ++i) {
    const int e = eid[base + i];
    const int src = (e < E0) ? srcArr[e] : (e - E0);
    s += q[src];
  }
  score[n] = bp[0] + dinvArr[n] * s;
}

// ---------------- per-graph top-K via in-LDS bitonic sort ----------------
// key = (ordered_uint(score) << 32) | (N_PER-1-i): descending sort reproduces
// lax.top_k exactly (larger score first, lower index first among ties).
__global__ __launch_bounds__(1024) void topk_kernel(const float* __restrict__ score,
                                                    int* __restrict__ perm) {
  constexpr int NPAD = 8192;
  __shared__ unsigned long long s[NPAD];   // 64 KiB
  const int b = blockIdx.x, tid = threadIdx.x;
  for (int i = tid; i < NPAD; i += 1024) {
    unsigned long long v = 0ull;
    if (i < N_PER) {
      const unsigned u = __float_as_uint(score[b * N_PER + i]);
      const unsigned okey = (u & 0x80000000u) ? ~u : (u | 0x80000000u);
      v = ((unsigned long long)okey << 32) | (unsigned)(N_PER - 1 - i);
    }
    s[i] = v;
  }
  __syncthreads();
  for (int k = 2; k <= NPAD; k <<= 1) {
    for (int j = k >> 1; j > 0; j >>= 1) {
      for (int t = tid; t < NPAD / 2; t += 1024) {
        const int i = ((t & ~(j - 1)) << 1) | (t & (j - 1));  // bit j of i is 0
        const int ixj = i | j;
        const bool up = ((i & k) == 0);
        const unsigned long long x = s[i], y = s[ixj];
        if (up ? (x < y) : (x > y)) { s[i] = y; s[ixj] = x; }
      }
      __syncthreads();
    }
  }
  for (int t = tid; t < KSEL; t += 1024) {
    const int idx = N_PER - 1 - (int)(s[t] & 0xFFFFFFFFull);
    perm[b * KSEL + t] = b * N_PER + idx;
  }
}

// ---------------- pooling: max || mean of h2*tanh(score) over selected ----------------
__global__ __launch_bounds__(256) void pool_kernel(const float* __restrict__ h2,
                                                   const float* __restrict__ score,
                                                   const int* __restrict__ perm,
                                                   float* __restrict__ pooled) {
  const int b = blockIdx.x;
  const int tid = threadIdx.x, wv = tid >> 6, lane = tid & 63;
  float mx = -FLT_MAX, sm = 0.f;
  for (int t = wv; t < KSEL; t += 4) {
    const int node = perm[b * KSEL + t];
    const float tv = tanhf(score[node]);
    const float x = h2[(size_t)node * DH + lane] * tv;
    mx = fmaxf(mx, x);
    sm += x;
  }
  __shared__ float smx[4][64], ssm[4][64];
  smx[wv][lane] = mx;
  ssm[wv][lane] = sm;
  __syncthreads();
  if (wv == 0) {
    const float M = fmaxf(fmaxf(smx[0][lane], smx[1][lane]), fmaxf(smx[2][lane], smx[3][lane]));
    const float S = ssm[0][lane] + ssm[1][lane] + ssm[2][lane] + ssm[3][lane];
    pooled[b * 128 + lane] = M;
    pooled[b * 128 + 64 + lane] = S / (float)KSEL;
  }
}

// ---------------- final linear + relu + log_softmax ----------------
__global__ __launch_bounds__(64) void final_kernel(const float* __restrict__ pooled,
                                                   const float* __restrict__ Wlin,
                                                   const float* __restrict__ blin,
                                                   float* __restrict__ out) {
  __shared__ float lg[NB][3];
  const int t = threadIdx.x;
  if (t < NB * 3) {
    const int b = t / 3, j = t % 3;
    float s = blin[j];
    for (int k = 0; k < 128; ++k) s = fmaf(pooled[b * 128 + k], Wlin[k * 3 + j], s);
    lg[b][j] = fmaxf(s, 0.f);
  }
  __syncthreads();
  if (t < NB) {
    const float a = lg[t][0], b2 = lg[t][1], c = lg[t][2];
    const float m = fmaxf(a, fmaxf(b2, c));
    const float lse = m + logf(expf(a - m) + expf(b2 - m) + expf(c - m));
    out[t * 3 + 0] = a - lse;
    out[t * 3 + 1] = b2 - lse;
    out[t * 3 + 2] = c - lse;
  }
}

// ---------------- launch ----------------
extern "C" void kernel_launch(void* const* d_in, const int* in_sizes, int n_in,
                              void* d_out, int out_size, void* d_ws, size_t ws_size,
                              hipStream_t stream) {
  (void)in_sizes; (void)n_in; (void)out_size; (void)ws_size;
  const float* x    = (const float*)d_in[0];
  const float* Wl1  = (const float*)d_in[1];
  const float* Wr1  = (const float*)d_in[2];
  const float* a1   = (const float*)d_in[3];
  const float* b1   = (const float*)d_in[4];
  const float* Wl2  = (const float*)d_in[5];
  const float* Wr2  = (const float*)d_in[6];
  const float* a2   = (const float*)d_in[7];
  const float* b2   = (const float*)d_in[8];
  const float* Wp   = (const float*)d_in[9];
  const float* bp   = (const float*)d_in[10];
  const float* Wlin = (const float*)d_in[11];
  const float* blin = (const float*)d_in[12];
  const int* ei     = (const int*)d_in[13];
  const int* srcArr = ei;          // edge_index[0]
  const int* dstArr = ei + E0;     // edge_index[1]
  float* out = (float*)d_out;

  // workspace layout (aliased; peak ~225 MB)
  char* w = (char*)d_ws;
  size_t off = 0;
  auto alloc = [&](size_t bytes) -> void* {
    void* p = w + off;
    off = (off + bytes + 255) & ~(size_t)255;
    return p;
  };
  float* big0   = (float*)alloc((size_t)NN * F1 * 4);  // xl1, later xl2|xr2|h2
  float* big1   = (float*)alloc((size_t)NN * F1 * 4);  // xr1, later h1
  float* logit1 = (float*)alloc((size_t)ET * 8 * 4);   // later logit2
  int* deg    = (int*)alloc((size_t)NN * 4);
  int* rowptr = (int*)alloc((size_t)(NN + 1) * 4);
  int* cnt    = (int*)alloc((size_t)NN * 4);
  int* eid    = (int*)alloc((size_t)ET * 4);
  float* q      = (float*)alloc((size_t)NN * 4);
  float* dinv   = (float*)alloc((size_t)NN * 4);
  float* score  = (float*)alloc((size_t)NN * 4);
  int* perm     = (int*)alloc((size_t)NB * KSEL * 4);
  float* pooled = (float*)alloc((size_t)NB * 128 * 4);

  float* xl1 = big0;
  float* xr1 = big1;
  float* h1  = big1;                          // overwrites xr1 (dead after edge1)
  float* xl2 = big0;                          // overwrites xl1 (dead after node1)
  float* xr2 = big0 + (size_t)NN * DH;
  float* h2  = big0 + (size_t)NN * DH * 2;
  float* logit2 = logit1;                     // logit1 dead after node1

  hipMemsetAsync(deg, 0, (size_t)NN * 4, stream);
  hipMemsetAsync(cnt, 0, (size_t)NN * 4, stream);

  deg_kernel<<<(ET + 255) / 256, 256, 0, stream>>>(dstArr, deg);
  scan_kernel<<<1, 1024, 0, stream>>>(deg, rowptr);
  fill_kernel<<<(ET + 255) / 256, 256, 0, stream>>>(dstArr, rowptr, cnt, eid);

  dim3 g1((NN + 63) / 64, F1 / 64);
  dual_gemm_kernel<<<g1, 256, 0, stream>>>(x, Wl1, Wr1, xl1, xr1, NN, DIN, F1);
  edge1_kernel<<<(ET + 3) / 4, 256, 0, stream>>>(xl1, xr1, srcArr, dstArr, a1, logit1);
  node1_kernel<<<NN, 512, 0, stream>>>(xl1, logit1, srcArr, rowptr, eid, b1, h1);

  dim3 g2((NN + 63) / 64, 1);
  dual_gemm_kernel<<<g2, 256, 0, stream>>>(h1, Wl2, Wr2, xl2, xr2, NN, F1, DH);
  edge2_kernel<<<(ET + 3) / 4, 256, 0, stream>>>(xl2, xr2, srcArr, dstArr, a2, logit2);
  node2_kernel<<<NN, 64, 0, stream>>>(xl2, logit2, srcArr, rowptr, eid, b2, Wp, h2, q, dinv);

  score_kernel<<<(NN + 255) / 256, 256, 0, stream>>>(srcArr, rowptr, eid, q, dinv, bp, score);
  topk_kernel<<<NB, 1024, 0, stream>>>(score, perm);
  pool_kernel<<<NB, 256, 0, stream>>>(h2, score, perm, pooled);
  final_kernel<<<1, 64, 0, stream>>>(pooled, Wlin, blin, out);
}

// Round 6
// 1723.730 us; speedup vs baseline: 1.6345x; 1.6345x over previous
//
#include <hip/hip_runtime.h>
#include <hip/hip_bf16.h>
#include <float.h>
#include <math.h>

// ---------------- problem constants (fixed by reference) ----------------
constexpr int N_PER = 5000, NB = 10, E_PER = 40000;
constexpr int NN = N_PER * NB;   // 50000 nodes
constexpr int E0 = E_PER * NB;   // 400000 edges (without self loops)
constexpr int ET = E0 + NN;      // 450000 edges incl. self loops
constexpr int DIN = 1024, DH = 64, HEADS = 8, F1 = 512;
constexpr int KSEL = 2500;
constexpr int MP = 50048;        // node rows padded to multiple of 128

#define DEV __device__ __forceinline__

typedef __attribute__((ext_vector_type(8))) short s8v;   // 8 bf16 (4 VGPRs)
typedef __attribute__((ext_vector_type(4))) float f4v;   // MFMA C/D frag

#define GLOAD16(gp, lp) __builtin_amdgcn_global_load_lds( \
    (const __attribute__((address_space(1))) unsigned int*)(gp), \
    (__attribute__((address_space(3))) unsigned int*)(lp), 16, 0, 0)

DEV float wave_sum(float v) {
#pragma unroll
  for (int off = 32; off; off >>= 1) v += __shfl_xor(v, off);
  return v;
}

// chop-split f32 -> bf16 hi + bf16 lo (residual exact, lo chopped; rel err ~2^-14)
DEV void split8(const float4& p, const float4& q, s8v& hi, s8v& lo) {
  const float f[8] = {p.x, p.y, p.z, p.w, q.x, q.y, q.z, q.w};
  unsigned hw[4], lw[4];
#pragma unroll
  for (int d = 0; d < 4; ++d) {
    const unsigned u0 = __float_as_uint(f[2 * d]);
    const unsigned u1 = __float_as_uint(f[2 * d + 1]);
    hw[d] = (u0 >> 16) | (u1 & 0xFFFF0000u);
    const float r0 = f[2 * d] - __uint_as_float(u0 & 0xFFFF0000u);
    const float r1 = f[2 * d + 1] - __uint_as_float(u1 & 0xFFFF0000u);
    lw[d] = (__float_as_uint(r0) >> 16) | (__float_as_uint(r1) & 0xFFFF0000u);
  }
  union U { unsigned w[4]; s8v v; };
  U a, b;
#pragma unroll
  for (int d = 0; d < 4; ++d) { a.w[d] = hw[d]; b.w[d] = lw[d]; }
  hi = a.v;
  lo = b.v;
}

// ---------------- CSR build ----------------
__global__ void deg_kernel(const int* __restrict__ dstArr, int* __restrict__ deg) {
  int e = blockIdx.x * 256 + threadIdx.x;
  if (e >= ET) return;
  int d = (e < E0) ? dstArr[e] : (e - E0);
  atomicAdd(&deg[d], 1);
}

__global__ __launch_bounds__(1024) void scan_kernel(const int* __restrict__ deg,
                                                    int* __restrict__ rowptr) {
  __shared__ int sh[1024];
  const int t = threadIdx.x;
  constexpr int CH = (NN + 1023) / 1024;  // 49
  const int b0 = t * CH;
  int sum = 0;
  for (int i = 0; i < CH; ++i) {
    const int idx = b0 + i;
    sum += (idx < NN) ? deg[idx] : 0;
  }
  sh[t] = sum;
  __syncthreads();
  for (int off = 1; off < 1024; off <<= 1) {
    int add = (t >= off) ? sh[t - off] : 0;
    __syncthreads();
    sh[t] += add;
    __syncthreads();
  }
  int run = (t == 0) ? 0 : sh[t - 1];
  for (int i = 0; i < CH; ++i) {
    const int idx = b0 + i;
    if (idx < NN) { rowptr[idx] = run; run += deg[idx]; }
  }
  if (t == 1023) rowptr[NN] = run;
}

__global__ void fill_kernel(const int* __restrict__ dstArr, const int* __restrict__ rowptr,
                            int* __restrict__ cnt, int* __restrict__ eid) {
  int e = blockIdx.x * 256 + threadIdx.x;
  if (e >= ET) return;
  int d = (e < E0) ? dstArr[e] : (e - E0);
  int pos = rowptr[d] + atomicAdd(&cnt[d], 1);
  eid[pos] = e;
}

// ---------------- weight transpose + split (tiny) ----------------
// BT1 [1024 n][1024 k]: n<512 -> Wl1 col n, else Wr1 col n-512
__global__ void wconv1_kernel(const float* __restrict__ Wl, const float* __restrict__ Wr,
                              short* __restrict__ BTh, short* __restrict__ BTl) {
  const int id = blockIdx.x * 256 + threadIdx.x;
  if (id >= 1024 * 1024) return;
  const int n = id >> 10, k = id & 1023;
  const float v = (n < 512) ? Wl[k * 512 + n] : Wr[k * 512 + (n - 512)];
  const unsigned u = __float_as_uint(v);
  BTh[id] = (short)(u >> 16);
  const float r = v - __uint_as_float(u & 0xFFFF0000u);
  BTl[id] = (short)(__float_as_uint(r) >> 16);
}

// BT2 [128 n][512 k]
__global__ void wconv2_kernel(const float* __restrict__ Wl, const float* __restrict__ Wr,
                              short* __restrict__ BTh, short* __restrict__ BTl) {
  const int id = blockIdx.x * 256 + threadIdx.x;
  if (id >= 128 * 512) return;
  const int n = id >> 9, k = id & 511;
  const float v = (n < 64) ? Wl[k * 64 + n] : Wr[k * 64 + (n - 64)];
  const unsigned u = __float_as_uint(v);
  BTh[id] = (short)(u >> 16);
  const float r = v - __uint_as_float(u & 0xFFFF0000u);
  BTl[id] = (short)(__float_as_uint(r) >> 16);
}

// ---------------- split-bf16 MFMA GEMM (3-term: AhBh + AlBh + AhBl) ----------------
// AF32=1: A f32 [*, lda], split in-register after LDS staging (rows clamped to NN-1).
// AF32=0: A pre-split bf16, Ah/Al with row stride lda (shorts).
// B: pre-split transposed bf16 BTh/BTl [n][k], row stride ldb.
// C: col < NHALF -> C0, else C1 (col-NHALF); both row stride ldc. 128x128 tile, BK=32.
template <int AF32>
__global__ __launch_bounds__(256) void gemm_kernel(
    const float* __restrict__ Af, const short* __restrict__ Ah,
    const short* __restrict__ Al, const int lda,
    const short* __restrict__ BTh, const short* __restrict__ BTl, const int ldb,
    float* C0, float* C1, const int NHALF, const int ldc, const int K, const int nby) {
  __shared__ char smem[32768];
  float* sAf = (float*)smem;                 // AF32: 128x32 f32 (16KB)
  short* sAh = (short*)smem;                 // else: 128x32 bf16 (8KB)
  short* sAl = (short*)(smem + 8192);        //       128x32 bf16 (8KB)
  short* sBh = (short*)(smem + 16384);
  short* sBl = (short*)(smem + 24576);

  // bijective XCD-chunked swizzle (col-block fastest within a chunk)
  const int nwg = gridDim.x, bid = blockIdx.x;
  const int qch = nwg >> 3, rch = nwg & 7;
  const int xcd = bid & 7, pos = bid >> 3;
  const int lb = (xcd < rch ? xcd * (qch + 1) : rch * (qch + 1) + (xcd - rch) * qch) + pos;
  const int bx = lb / nby, by = lb - bx * nby;

  const int row0 = bx * 128, col0 = by * 128;
  const int tid = threadIdx.x, lane = tid & 63, w = tid >> 6;
  const int wm = w >> 1, wn = w & 1;

  // staging address precompute. B tile: 128 rows x 64B (4 chunks), 2 shots.
  size_t gB[2];
  int lB[2];
#pragma unroll
  for (int s = 0; s < 2; ++s) {
    const int c = s * 256 + tid, r = c >> 2, sl = c & 3;
    const int cc = sl ^ ((r >> 1) & 3);
    gB[s] = (size_t)(col0 + r) * ldb + (size_t)(cc << 3);
    lB[s] = (s * 256 + w * 64) << 3;
  }
  size_t gA[4];
  int lA[4];
  if (AF32) {  // A tile: 128 rows x 128B (8 chunks), 4 shots
#pragma unroll
    for (int s = 0; s < 4; ++s) {
      const int c = s * 256 + tid, r = c >> 3, sl = c & 7;
      const int cc = sl ^ (r & 7);
      const int grow = min(row0 + r, NN - 1);
      gA[s] = (size_t)grow * lda + (size_t)(cc << 2);
      lA[s] = (s * 256 + w * 64) << 2;
    }
  } else {  // A tile bf16: like B, 2 shots each for hi/lo
#pragma unroll
    for (int s = 0; s < 2; ++s) {
      const int c = s * 256 + tid, r = c >> 2, sl = c & 3;
      const int cc = sl ^ ((r >> 1) & 3);
      const int grow = min(row0 + r, NN - 1);
      gA[s] = (size_t)grow * lda + (size_t)(cc << 3);
      lA[s] = (s * 256 + w * 64) << 3;
    }
  }

  // fragment LDS offsets (swizzle-aware)
  int aof0[4], aof1[4], bof[4];
#pragma unroll
  for (int i = 0; i < 4; ++i) {
    const int r = wm * 64 + i * 16 + (lane & 15);
    if (AF32) {
      const int cc0 = (lane >> 4) << 1;
      aof0[i] = (r << 5) + ((cc0 ^ (r & 7)) << 2);
      aof1[i] = (r << 5) + (((cc0 + 1) ^ (r & 7)) << 2);
    } else {
      aof0[i] = (r << 5) + (((lane >> 4) ^ ((r >> 1) & 3)) << 3);
    }
    const int cb = wn * 64 + i * 16 + (lane & 15);
    bof[i] = (cb << 5) + (((lane >> 4) ^ ((cb >> 1) & 3)) << 3);
  }

  f4v acc[4][4];
#pragma unroll
  for (int i = 0; i < 4; ++i)
#pragma unroll
    for (int j = 0; j < 4; ++j) acc[i][j] = (f4v){0.f, 0.f, 0.f, 0.f};

  for (int kt = 0; kt < K; kt += 32) {
    __syncthreads();
    if (AF32) {
#pragma unroll
      for (int s = 0; s < 4; ++s) GLOAD16(Af + gA[s] + kt, sAf + lA[s]);
    } else {
#pragma unroll
      for (int s = 0; s < 2; ++s) {
        GLOAD16(Ah + gA[s] + kt, sAh + lA[s]);
        GLOAD16(Al + gA[s] + kt, sAl + lA[s]);
      }
    }
#pragma unroll
    for (int s = 0; s < 2; ++s) {
      GLOAD16(BTh + gB[s] + kt, sBh + lB[s]);
      GLOAD16(BTl + gB[s] + kt, sBl + lB[s]);
    }
    __syncthreads();
    s8v ah4[4], al4[4], bh4[4], bl4[4];
#pragma unroll
    for (int i = 0; i < 4; ++i) {
      if (AF32) {
        const float4 p = *(const float4*)&sAf[aof0[i]];
        const float4 q2 = *(const float4*)&sAf[aof1[i]];
        split8(p, q2, ah4[i], al4[i]);
      } else {
        ah4[i] = *(const s8v*)&sAh[aof0[i]];
        al4[i] = *(const s8v*)&sAl[aof0[i]];
      }
      bh4[i] = *(const s8v*)&sBh[bof[i]];
      bl4[i] = *(const s8v*)&sBl[bof[i]];
    }
#pragma unroll
    for (int i = 0; i < 4; ++i)
#pragma unroll
      for (int j = 0; j < 4; ++j) {
        acc[i][j] = __builtin_amdgcn_mfma_f32_16x16x32_bf16(ah4[i], bh4[j], acc[i][j], 0, 0, 0);
        acc[i][j] = __builtin_amdgcn_mfma_f32_16x16x32_bf16(al4[i], bh4[j], acc[i][j], 0, 0, 0);
        acc[i][j] = __builtin_amdgcn_mfma_f32_16x16x32_bf16(ah4[i], bl4[j], acc[i][j], 0, 0, 0);
      }
  }
  // epilogue: C/D layout col=lane&15, row=(lane>>4)*4+q (m89-verified)
  float* Cb;
  int cb0;
  if (col0 < NHALF) { Cb = C0; cb0 = col0; } else { Cb = C1; cb0 = col0 - NHALF; }
  const int crow = (lane >> 4) << 2, ccol = lane & 15;
#pragma unroll
  for (int i = 0; i < 4; ++i) {
    const int rb = row0 + wm * 64 + i * 16 + crow;
#pragma unroll
    for (int j = 0; j < 4; ++j) {
      const int cc = cb0 + wn * 64 + j * 16 + ccol;
#pragma unroll
      for (int qq = 0; qq < 4; ++qq)
        Cb[(size_t)(rb + qq) * ldc + cc] = acc[i][j][qq];
    }
  }
}

// ---------------- fused GATv2 layer 1: logits + online softmax + agg + ELU ----------------
// one node per block; 512 threads (8 waves). h1 (split bf16, row = hi[512]||lo[512])
// is written IN PLACE over xr1 (only block n ever touches row n of that buffer).
__global__ __launch_bounds__(512) void node1_kernel(
    const float* __restrict__ xl1, char* xr1h1_base, const int* __restrict__ srcArr,
    const int* __restrict__ rowptr, const int* __restrict__ eid,
    const float* __restrict__ a1, const float* __restrict__ b1) {
  const float* xr1 = (const float*)xr1h1_base;
  short* h1s = (short*)xr1h1_base;
  const int n = blockIdx.x;
  const int tid = threadIdx.x, w = tid >> 6, lane = tid & 63;
  const int base = rowptr[n], deg = rowptr[n + 1] - base;
  __shared__ float rows[8][512];  // 16 KB
  __shared__ float lg[8][8];      // [edge-in-chunk][head]
  float xr_r[8], a1_r[8];
#pragma unroll
  for (int t = 0; t < 8; ++t) {
    xr_r[t] = xr1[(size_t)n * 512 + t * 64 + lane];
    a1_r[t] = a1[t * 64 + lane];
  }
  float m = -FLT_MAX, s = 0.f, acc = 0.f;
  const int h = w;
  for (int c0 = 0; c0 < deg; c0 += 8) {
    const int nc = min(8, deg - c0);
    __syncthreads();  // prev chunk consumed; also orders xr reads before h1 store
    if (w < nc) {
      const int e = eid[base + c0 + w];
      const int src = (e < E0) ? srcArr[e] : (e - E0);
      const float* xp = xl1 + (size_t)src * 512;
      float r[8];
#pragma unroll
      for (int t = 0; t < 8; ++t) {
        r[t] = xp[t * 64 + lane];
        rows[w][t * 64 + lane] = r[t];
      }
#pragma unroll
      for (int t = 0; t < 8; ++t) {
        float v = r[t] + xr_r[t];
        v = (v > 0.f) ? v : 0.2f * v;  // leaky_relu 0.2
        v = wave_sum(v * a1_r[t]);
        if (lane == 0) lg[w][t] = v;
      }
    }
    __syncthreads();
    float mc = -FLT_MAX;
    for (int i = 0; i < nc; ++i) mc = fmaxf(mc, lg[i][h]);
    if (mc > m) {  // wave-uniform
      const float f = __expf(m - mc);
      s *= f;
      acc *= f;
      m = mc;
    }
    for (int i = 0; i < nc; ++i) {
      const float p = __expf(lg[i][h] - m);
      s += p;
      acc = fmaf(p, rows[i][tid], acc);
    }
  }
  const float v = acc / (s + 1e-16f) + b1[tid];
  const float hv = (v > 0.f) ? v : expm1f(v);  // ELU
  const unsigned u = __float_as_uint(hv);
  h1s[(size_t)n * 1024 + tid] = (short)(u >> 16);
  const float rr = hv - __uint_as_float(u & 0xFFFF0000u);
  h1s[(size_t)n * 1024 + 512 + tid] = (short)(__float_as_uint(rr) >> 16);
}

// ---------------- fused GATv2 layer 2 + SELU + score projection ----------------
__global__ __launch_bounds__(256) void node2_kernel(
    const float* __restrict__ xlr2, const int* __restrict__ srcArr,
    const int* __restrict__ rowptr, const int* __restrict__ eid,
    const float* __restrict__ a2, const float* __restrict__ b2,
    const float* __restrict__ Wp, float* __restrict__ h2,
    float* __restrict__ q, float* __restrict__ dinvArr) {
  const int n = blockIdx.x * 4 + (threadIdx.x >> 6);
  const int lane = threadIdx.x & 63;
  if (n >= NN) return;
  const int base = rowptr[n], deg = rowptr[n + 1] - base;
  const float xr = xlr2[(size_t)n * 128 + 64 + lane];
  const float av = a2[lane];
  float m = -FLT_MAX, s = 0.f, acc = 0.f;
  for (int i = 0; i < deg; ++i) {
    const int e = eid[base + i];
    const int src = (e < E0) ? srcArr[e] : (e - E0);
    const float xlv = xlr2[(size_t)src * 128 + lane];
    float v = xlv + xr;
    v = (v > 0.f) ? v : 0.2f * v;
    const float lgt = wave_sum(v * av);
    if (lgt > m) {
      const float f = __expf(m - lgt);
      s = s * f + 1.f;
      acc = acc * f + xlv;
      m = lgt;
    } else {
      const float p = __expf(lgt - m);
      s += p;
      acc = fmaf(p, xlv, acc);
    }
  }
  const float v = acc / (s + 1e-16f) + b2[lane];
  constexpr float SC = 1.0507009873554804934f, AL = 1.6732632423543772848f;
  const float hv = (v > 0.f) ? SC * v : SC * AL * expm1f(v);  // SELU
  h2[(size_t)n * 64 + lane] = hv;
  const float p = wave_sum(hv * Wp[lane]);
  if (lane == 0) {
    const float di = rsqrtf((float)deg);
    q[n] = di * p;
    dinvArr[n] = di;
  }
}

// ---------------- GCN score ----------------
__global__ void score_kernel(const int* __restrict__ srcArr, const int* __restrict__ rowptr,
                             const int* __restrict__ eid, const float* __restrict__ q,
                             const float* __restrict__ dinvArr, const float* __restrict__ bp,
                             float* __restrict__ score) {
  const int n = blockIdx.x * 256 + threadIdx.x;
  if (n >= NN) return;
  const int base = rowptr[n], deg = rowptr[n + 1] - base;
  float s = 0.f;
  for (int i = 0; i < deg; ++i) {
    const int e = eid[base + i];
    const int src = (e < E0) ? srcArr[e] : (e - E0);
    s += q[src];
  }
  score[n] = bp[0] + dinvArr[n] * s;
}

// ---------------- per-graph top-K via in-LDS bitonic sort ----------------
__global__ __launch_bounds__(1024) void topk_kernel(const float* __restrict__ score,
                                                    int* __restrict__ perm) {
  constexpr int NPAD = 8192;
  __shared__ unsigned long long s[NPAD];  // 64 KiB
  const int b = blockIdx.x, tid = threadIdx.x;
  for (int i = tid; i < NPAD; i += 1024) {
    unsigned long long v = 0ull;
    if (i < N_PER) {
      const unsigned u = __float_as_uint(score[b * N_PER + i]);
      const unsigned okey = (u & 0x80000000u) ? ~u : (u | 0x80000000u);
      v = ((unsigned long long)okey << 32) | (unsigned)(N_PER - 1 - i);
    }
    s[i] = v;
  }
  __syncthreads();
  for (int k = 2; k <= NPAD; k <<= 1) {
    for (int j = k >> 1; j > 0; j >>= 1) {
      for (int t = tid; t < NPAD / 2; t += 1024) {
        const int i = ((t & ~(j - 1)) << 1) | (t & (j - 1));
        const int ixj = i | j;
        const bool up = ((i & k) == 0);
        const unsigned long long x = s[i], y = s[ixj];
        if (up ? (x < y) : (x > y)) { s[i] = y; s[ixj] = x; }
      }
      __syncthreads();
    }
  }
  for (int t = tid; t < KSEL; t += 1024) {
    const int idx = N_PER - 1 - (int)(s[t] & 0xFFFFFFFFull);
    perm[b * KSEL + t] = b * N_PER + idx;
  }
}

// ---------------- pooling: max || mean of h2*tanh(score) over selected ----------------
__global__ __launch_bounds__(256) void pool_kernel(const float* __restrict__ h2,
                                                   const float* __restrict__ score,
                                                   const int* __restrict__ perm,
                                                   float* __restrict__ pooled) {
  const int b = blockIdx.x;
  const int tid = threadIdx.x, wv = tid >> 6, lane = tid & 63;
  float mx = -FLT_MAX, sm = 0.f;
  for (int t = wv; t < KSEL; t += 4) {
    const int node = perm[b * KSEL + t];
    const float tv = tanhf(score[node]);
    const float x = h2[(size_t)node * DH + lane] * tv;
    mx = fmaxf(mx, x);
    sm += x;
  }
  __shared__ float smx[4][64], ssm[4][64];
  smx[wv][lane] = mx;
  ssm[wv][lane] = sm;
  __syncthreads();
  if (wv == 0) {
    const float M = fmaxf(fmaxf(smx[0][lane], smx[1][lane]), fmaxf(smx[2][lane], smx[3][lane]));
    const float S = ssm[0][lane] + ssm[1][lane] + ssm[2][lane] + ssm[3][lane];
    pooled[b * 128 + lane] = M;
    pooled[b * 128 + 64 + lane] = S / (float)KSEL;
  }
}

// ---------------- final linear + relu + log_softmax ----------------
__global__ __launch_bounds__(64) void final_kernel(const float* __restrict__ pooled,
                                                   const float* __restrict__ Wlin,
                                                   const float* __restrict__ blin,
                                                   float* __restrict__ out) {
  __shared__ float lg[NB][3];
  const int t = threadIdx.x;
  if (t < NB * 3) {
    const int b = t / 3, j = t % 3;
    float s = blin[j];
    for (int k = 0; k < 128; ++k) s = fmaf(pooled[b * 128 + k], Wlin[k * 3 + j], s);
    lg[b][j] = fmaxf(s, 0.f);
  }
  __syncthreads();
  if (t < NB) {
    const float a = lg[t][0], b2 = lg[t][1], c = lg[t][2];
    const float m = fmaxf(a, fmaxf(b2, c));
    const float lse = m + logf(expf(a - m) + expf(b2 - m) + expf(c - m));
    out[t * 3 + 0] = a - lse;
    out[t * 3 + 1] = b2 - lse;
    out[t * 3 + 2] = c - lse;
  }
}

// ---------------- launch ----------------
extern "C" void kernel_launch(void* const* d_in, const int* in_sizes, int n_in,
                              void* d_out, int out_size, void* d_ws, size_t ws_size,
                              hipStream_t stream) {
  (void)in_sizes; (void)n_in; (void)out_size; (void)ws_size;
  const float* x    = (const float*)d_in[0];
  const float* Wl1  = (const float*)d_in[1];
  const float* Wr1  = (const float*)d_in[2];
  const float* a1   = (const float*)d_in[3];
  const float* b1   = (const float*)d_in[4];
  const float* Wl2  = (const float*)d_in[5];
  const float* Wr2  = (const float*)d_in[6];
  const float* a2   = (const float*)d_in[7];
  const float* b2   = (const float*)d_in[8];
  const float* Wp   = (const float*)d_in[9];
  const float* bp   = (const float*)d_in[10];
  const float* Wlin = (const float*)d_in[11];
  const float* blin = (const float*)d_in[12];
  const int* ei     = (const int*)d_in[13];
  const int* srcArr = ei;
  const int* dstArr = ei + E0;
  float* out = (float*)d_out;

  // workspace layout (~212.5 MB, within round-0-proven budget)
  char* w = (char*)d_ws;
  size_t off = 0;
  auto alloc = [&](size_t bytes) -> void* {
    void* p = w + off;
    off = (off + bytes + 255) & ~(size_t)255;
    return p;
  };
  float* xl1   = (float*)alloc((size_t)MP * 512 * 4);  // later: xlr2 | h2
  char*  xr1h1 = (char*)alloc((size_t)MP * 512 * 4);   // xr1 f32 -> h1 split bf16
  short* BT1h = (short*)alloc((size_t)1024 * 1024 * 2);
  short* BT1l = (short*)alloc((size_t)1024 * 1024 * 2);
  short* BT2h = (short*)alloc((size_t)128 * 512 * 2);
  short* BT2l = (short*)alloc((size_t)128 * 512 * 2);
  int* deg    = (int*)alloc((size_t)NN * 4);
  int* rowptr = (int*)alloc((size_t)(NN + 1) * 4);
  int* cnt    = (int*)alloc((size_t)NN * 4);
  int* eid    = (int*)alloc((size_t)ET * 4);
  float* q      = (float*)alloc((size_t)NN * 4);
  float* dinv   = (float*)alloc((size_t)NN * 4);
  float* score  = (float*)alloc((size_t)NN * 4);
  int* perm     = (int*)alloc((size_t)NB * KSEL * 4);
  float* pooled = (float*)alloc((size_t)NB * 128 * 4);

  float* xr1  = (float*)xr1h1;
  short* h1s  = (short*)xr1h1;
  float* xlr2 = xl1;                                     // aliases xl1 (dead after node1)
  float* h2   = (float*)((char*)xl1 + (size_t)MP * 128 * 4);

  hipMemsetAsync(deg, 0, (size_t)NN * 4, stream);
  hipMemsetAsync(cnt, 0, (size_t)NN * 4, stream);

  deg_kernel<<<(ET + 255) / 256, 256, 0, stream>>>(dstArr, deg);
  scan_kernel<<<1, 1024, 0, stream>>>(deg, rowptr);
  fill_kernel<<<(ET + 255) / 256, 256, 0, stream>>>(dstArr, rowptr, cnt, eid);

  wconv1_kernel<<<(1024 * 1024) / 256, 256, 0, stream>>>(Wl1, Wr1, BT1h, BT1l);
  wconv2_kernel<<<(128 * 512) / 256, 256, 0, stream>>>(Wl2, Wr2, BT2h, BT2l);

  // layer-1 GEMM: [MP,1024] x [1024,1024] -> xl1 | xr1
  gemm_kernel<1><<<(MP / 128) * 8, 256, 0, stream>>>(
      x, nullptr, nullptr, DIN, BT1h, BT1l, 1024, xl1, xr1, 512, 512, 1024, 8);
  node1_kernel<<<NN, 512, 0, stream>>>(xl1, xr1h1, srcArr, rowptr, eid, a1, b1);

  // layer-2 GEMM: [MP,512] x [512,128] -> xlr2
  gemm_kernel<0><<<MP / 128, 256, 0, stream>>>(
      nullptr, h1s, h1s + 512, 1024, BT2h, BT2l, 512, xlr2, xlr2, 128, 128, 512, 1);
  node2_kernel<<<(NN + 3) / 4, 256, 0, stream>>>(xlr2, srcArr, rowptr, eid, a2, b2, Wp,
                                                 h2, q, dinv);

  score_kernel<<<(NN + 255) / 256, 256, 0, stream>>>(srcArr, rowptr, eid, q, dinv, bp, score);
  topk_kernel<<<NB, 1024, 0, stream>>>(score, perm);
  pool_kernel<<<NB, 256, 0, stream>>>(h2, score, perm, pooled);
  final_kernel<<<1, 64, 0, stream>>>(pooled, Wlin, blin, out);
}

// Round 7
// 1297.640 us; speedup vs baseline: 2.1712x; 1.3284x over previous
//
#include <hip/hip_runtime.h>
#include <hip/hip_bf16.h>
#include <float.h>
#include <math.h>

// ---------------- problem constants (fixed by reference) ----------------
constexpr int N_PER = 5000, NB = 10, E_PER = 40000;
constexpr int NN = N_PER * NB;   // 50000 nodes
constexpr int E0 = E_PER * NB;   // 400000 edges (without self loops)
constexpr int ET = E0 + NN;      // 450000 edges incl. self loops
constexpr int DIN = 1024, DH = 64, HEADS = 8, F1 = 512;
constexpr int KSEL = 2500;
constexpr int MP = 50048;        // node rows padded to multiple of 128

#define DEV __device__ __forceinline__

typedef __attribute__((ext_vector_type(8))) short s8v;   // 8 bf16 (4 VGPRs)
typedef __attribute__((ext_vector_type(4))) float f4v;   // MFMA C/D frag

#define GLOAD16(gp, lp) __builtin_amdgcn_global_load_lds( \
    (const __attribute__((address_space(1))) unsigned int*)(gp), \
    (__attribute__((address_space(3))) unsigned int*)(lp), 16, 0, 0)

DEV float wave_sum(float v) {
#pragma unroll
  for (int off = 32; off; off >>= 1) v += __shfl_xor(v, off);
  return v;
}

// chop-pack 8 f32 -> 8 bf16 (hot path; bf16 chop err ~2^-9, output-insensitive)
DEV s8v pack_hi8(const float4& p, const float4& q) {
  const float f[8] = {p.x, p.y, p.z, p.w, q.x, q.y, q.z, q.w};
  union U { unsigned w[4]; s8v v; } u;
#pragma unroll
  for (int d = 0; d < 4; ++d)
    u.w[d] = (__float_as_uint(f[2 * d]) >> 16) | (__float_as_uint(f[2 * d + 1]) & 0xFFFF0000u);
  return u.v;
}

// ---------------- CSR build ----------------
__global__ void deg_kernel(const int* __restrict__ dstArr, int* __restrict__ deg) {
  int e = blockIdx.x * 256 + threadIdx.x;
  if (e >= ET) return;
  int d = (e < E0) ? dstArr[e] : (e - E0);
  atomicAdd(&deg[d], 1);
}

__global__ __launch_bounds__(1024) void scan_kernel(const int* __restrict__ deg,
                                                    int* __restrict__ rowptr) {
  __shared__ int sh[1024];
  const int t = threadIdx.x;
  constexpr int CH = (NN + 1023) / 1024;  // 49
  const int b0 = t * CH;
  int sum = 0;
  for (int i = 0; i < CH; ++i) {
    const int idx = b0 + i;
    sum += (idx < NN) ? deg[idx] : 0;
  }
  sh[t] = sum;
  __syncthreads();
  for (int off = 1; off < 1024; off <<= 1) {
    int add = (t >= off) ? sh[t - off] : 0;
    __syncthreads();
    sh[t] += add;
    __syncthreads();
  }
  int run = (t == 0) ? 0 : sh[t - 1];
  for (int i = 0; i < CH; ++i) {
    const int idx = b0 + i;
    if (idx < NN) { rowptr[idx] = run; run += deg[idx]; }
  }
  if (t == 1023) rowptr[NN] = run;
}

__global__ void fill_kernel(const int* __restrict__ dstArr, const int* __restrict__ rowptr,
                            int* __restrict__ cnt, int* __restrict__ eid) {
  int e = blockIdx.x * 256 + threadIdx.x;
  if (e >= ET) return;
  int d = (e < E0) ? dstArr[e] : (e - E0);
  int pos = rowptr[d] + atomicAdd(&cnt[d], 1);
  eid[pos] = e;
}

// ---------------- weight transpose -> bf16 (RNE, tiny) ----------------
// BT1 [1024 n][1024 k]: n<512 -> Wl1 col n, else Wr1 col n-512
__global__ void wconv1_kernel(const float* __restrict__ Wl, const float* __restrict__ Wr,
                              short* __restrict__ BTh) {
  const int id = blockIdx.x * 256 + threadIdx.x;
  if (id >= 1024 * 1024) return;
  const int n = id >> 10, k = id & 1023;
  const float v = (n < 512) ? Wl[k * 512 + n] : Wr[k * 512 + (n - 512)];
  const unsigned u = __float_as_uint(v);
  BTh[id] = (short)((u + 0x7FFFu + ((u >> 16) & 1u)) >> 16);
}

// BT2 [128 n][512 k]
__global__ void wconv2_kernel(const float* __restrict__ Wl, const float* __restrict__ Wr,
                              short* __restrict__ BTh) {
  const int id = blockIdx.x * 256 + threadIdx.x;
  if (id >= 128 * 512) return;
  const int n = id >> 9, k = id & 511;
  const float v = (n < 64) ? Wl[k * 64 + n] : Wr[k * 64 + (n - 64)];
  const unsigned u = __float_as_uint(v);
  BTh[id] = (short)((u + 0x7FFFu + ((u >> 16) & 1u)) >> 16);
}

// ---------------- bf16 MFMA GEMM, A f32 (in-register chop to bf16) ----------------
// A f32 [*, lda], rows clamped to NN-1. B pre-converted transposed bf16 [n][k] stride ldb.
// C: col < NHALF -> C0, else C1 (col-NHALF); both row stride ldc. 128x128 tile, BK=32.
__global__ __launch_bounds__(256) void gemm_kernel(
    const float* __restrict__ Af, const int lda,
    const short* __restrict__ BTh, const int ldb,
    float* C0, float* C1, const int NHALF, const int ldc, const int K, const int nby) {
  __shared__ char smem[24576];
  float* sAf = (float*)smem;                 // 128x32 f32 (16KB)
  short* sBh = (short*)(smem + 16384);       // 128x32 bf16 (8KB)

  // bijective XCD-chunked swizzle (col-block fastest within a chunk)
  const int nwg = gridDim.x, bid = blockIdx.x;
  const int qch = nwg >> 3, rch = nwg & 7;
  const int xcd = bid & 7, pos = bid >> 3;
  const int lb = (xcd < rch ? xcd * (qch + 1) : rch * (qch + 1) + (xcd - rch) * qch) + pos;
  const int bx = lb / nby, by = lb - bx * nby;

  const int row0 = bx * 128, col0 = by * 128;
  const int tid = threadIdx.x, lane = tid & 63, w = tid >> 6;
  const int wm = w >> 1, wn = w & 1;

  // staging address precompute. B tile: 128 rows x 64B (4 chunks), 2 shots.
  size_t gB[2];
  int lB[2];
#pragma unroll
  for (int s = 0; s < 2; ++s) {
    const int c = s * 256 + tid, r = c >> 2, sl = c & 3;
    const int cc = sl ^ ((r >> 1) & 3);
    gB[s] = (size_t)(col0 + r) * ldb + (size_t)(cc << 3);
    lB[s] = (s * 256 + w * 64) << 3;
  }
  // A tile: 128 rows x 128B (8 chunks), 4 shots
  size_t gA[4];
  int lA[4];
#pragma unroll
  for (int s = 0; s < 4; ++s) {
    const int c = s * 256 + tid, r = c >> 3, sl = c & 7;
    const int cc = sl ^ (r & 7);
    const int grow = min(row0 + r, NN - 1);
    gA[s] = (size_t)grow * lda + (size_t)(cc << 2);
    lA[s] = (s * 256 + w * 64) << 2;
  }

  // fragment LDS offsets (swizzle-aware)
  int aof0[4], aof1[4], bof[4];
#pragma unroll
  for (int i = 0; i < 4; ++i) {
    const int r = wm * 64 + i * 16 + (lane & 15);
    const int cc0 = (lane >> 4) << 1;
    aof0[i] = (r << 5) + ((cc0 ^ (r & 7)) << 2);
    aof1[i] = (r << 5) + (((cc0 + 1) ^ (r & 7)) << 2);
    const int cb = wn * 64 + i * 16 + (lane & 15);
    bof[i] = (cb << 5) + (((lane >> 4) ^ ((cb >> 1) & 3)) << 3);
  }

  f4v acc[4][4];
#pragma unroll
  for (int i = 0; i < 4; ++i)
#pragma unroll
    for (int j = 0; j < 4; ++j) acc[i][j] = (f4v){0.f, 0.f, 0.f, 0.f};

  for (int kt = 0; kt < K; kt += 32) {
    __syncthreads();
#pragma unroll
    for (int s = 0; s < 4; ++s) GLOAD16(Af + gA[s] + kt, sAf + lA[s]);
#pragma unroll
    for (int s = 0; s < 2; ++s) GLOAD16(BTh + gB[s] + kt, sBh + lB[s]);
    __syncthreads();
    s8v ah4[4], bh4[4];
#pragma unroll
    for (int i = 0; i < 4; ++i) {
      const float4 p = *(const float4*)&sAf[aof0[i]];
      const float4 q2 = *(const float4*)&sAf[aof1[i]];
      ah4[i] = pack_hi8(p, q2);
      bh4[i] = *(const s8v*)&sBh[bof[i]];
    }
#pragma unroll
    for (int i = 0; i < 4; ++i)
#pragma unroll
      for (int j = 0; j < 4; ++j)
        acc[i][j] = __builtin_amdgcn_mfma_f32_16x16x32_bf16(ah4[i], bh4[j], acc[i][j], 0, 0, 0);
  }
  // epilogue: C/D layout col=lane&15, row=(lane>>4)*4+q (m89-verified)
  float* Cb;
  int cb0;
  if (col0 < NHALF) { Cb = C0; cb0 = col0; } else { Cb = C1; cb0 = col0 - NHALF; }
  const int crow = (lane >> 4) << 2, ccol = lane & 15;
#pragma unroll
  for (int i = 0; i < 4; ++i) {
    const int rb = row0 + wm * 64 + i * 16 + crow;
#pragma unroll
    for (int j = 0; j < 4; ++j) {
      const int cc = cb0 + wn * 64 + j * 16 + ccol;
#pragma unroll
      for (int qq = 0; qq < 4; ++qq)
        Cb[(size_t)(rb + qq) * ldc + cc] = acc[i][j][qq];
    }
  }
}

// ---------------- fused GATv2 layer 1: wave-per-node, all in registers ----------------
// One wave owns one node: 64 lanes x 8 contiguous channels = 512. Each lane's 8
// channels lie in one head (head = lane>>3) -> logit = 8 FMA + 3-shuffle group
// reduce. Branchless online softmax. h1 (f32) written IN PLACE over xr1 (same
// wave reads xr first; data-dependent ordering; row owned by this wave only).
__global__ __launch_bounds__(256) void node1_kernel(
    const float* __restrict__ xl1, float* xr1h1, const int* __restrict__ srcArr,
    const int* __restrict__ rowptr, const int* __restrict__ eid,
    const float* __restrict__ a1, const float* __restrict__ b1) {
  const int n = blockIdx.x * 4 + (threadIdx.x >> 6);
  const int lane = threadIdx.x & 63;
  if (n >= NN) return;
  const int base = rowptr[n], deg = rowptr[n + 1] - base;
  const int c0 = lane * 8;
  const float* xrp = xr1h1 + (size_t)n * 512 + c0;
  const float4 xrA = *(const float4*)(xrp);
  const float4 xrB = *(const float4*)(xrp + 4);
  const float4 a1A = *(const float4*)(a1 + c0);
  const float4 a1B = *(const float4*)(a1 + c0 + 4);
  const float xr_r[8] = {xrA.x, xrA.y, xrA.z, xrA.w, xrB.x, xrB.y, xrB.z, xrB.w};
  const float a1_r[8] = {a1A.x, a1A.y, a1A.z, a1A.w, a1B.x, a1B.y, a1B.z, a1B.w};
  float m = -FLT_MAX, s = 0.f;
  float acc[8] = {0.f, 0.f, 0.f, 0.f, 0.f, 0.f, 0.f, 0.f};
  for (int i = 0; i < deg; ++i) {
    const int e = eid[base + i];
    const int src = (e < E0) ? srcArr[e] : (e - E0);
    const float* xp = xl1 + (size_t)src * 512 + c0;
    const float4 rA = *(const float4*)(xp);
    const float4 rB = *(const float4*)(xp + 4);
    const float r[8] = {rA.x, rA.y, rA.z, rA.w, rB.x, rB.y, rB.z, rB.w};
    float part = 0.f;
#pragma unroll
    for (int j = 0; j < 8; ++j) {
      float v = r[j] + xr_r[j];
      v = (v > 0.f) ? v : 0.2f * v;  // leaky_relu 0.2
      part = fmaf(v, a1_r[j], part);
    }
    part += __shfl_xor(part, 1);
    part += __shfl_xor(part, 2);
    part += __shfl_xor(part, 4);   // logit of head lane>>3, same on its 8 lanes
    const float mn = fmaxf(m, part);
    const float f = __expf(m - mn);   // 1 if m unchanged; 0 on first iter
    const float p = __expf(part - mn);
    s = s * f + p;
#pragma unroll
    for (int j = 0; j < 8; ++j) acc[j] = fmaf(acc[j], f, p * r[j]);
    m = mn;
  }
  const float inv = 1.f / (s + 1e-16f);
  const float4 b1A = *(const float4*)(b1 + c0);
  const float4 b1B = *(const float4*)(b1 + c0 + 4);
  const float b1_r[8] = {b1A.x, b1A.y, b1A.z, b1A.w, b1B.x, b1B.y, b1B.z, b1B.w};
  float o[8];
#pragma unroll
  for (int j = 0; j < 8; ++j) {
    const float v = acc[j] * inv + b1_r[j];
    o[j] = (v > 0.f) ? v : expm1f(v);  // ELU
  }
  float* hp = xr1h1 + (size_t)n * 512 + c0;  // overwrite xr1 row with h1 (f32)
  *(float4*)(hp) = make_float4(o[0], o[1], o[2], o[3]);
  *(float4*)(hp + 4) = make_float4(o[4], o[5], o[6], o[7]);
}

// ---------------- fused GATv2 layer 2 + SELU + score projection ----------------
__global__ __launch_bounds__(256) void node2_kernel(
    const float* __restrict__ xlr2, const int* __restrict__ srcArr,
    const int* __restrict__ rowptr, const int* __restrict__ eid,
    const float* __restrict__ a2, const float* __restrict__ b2,
    const float* __restrict__ Wp, float* __restrict__ h2,
    float* __restrict__ q, float* __restrict__ dinvArr) {
  const int n = blockIdx.x * 4 + (threadIdx.x >> 6);
  const int lane = threadIdx.x & 63;
  if (n >= NN) return;
  const int base = rowptr[n], deg = rowptr[n + 1] - base;
  const float xr = xlr2[(size_t)n * 128 + 64 + lane];
  const float av = a2[lane];
  float m = -FLT_MAX, s = 0.f, acc = 0.f;
  for (int i = 0; i < deg; ++i) {
    const int e = eid[base + i];
    const int src = (e < E0) ? srcArr[e] : (e - E0);
    const float xlv = xlr2[(size_t)src * 128 + lane];
    float v = xlv + xr;
    v = (v > 0.f) ? v : 0.2f * v;
    const float lgt = wave_sum(v * av);
    if (lgt > m) {
      const float f = __expf(m - lgt);
      s = s * f + 1.f;
      acc = acc * f + xlv;
      m = lgt;
    } else {
      const float p = __expf(lgt - m);
      s += p;
      acc = fmaf(p, xlv, acc);
    }
  }
  const float v = acc / (s + 1e-16f) + b2[lane];
  constexpr float SC = 1.0507009873554804934f, AL = 1.6732632423543772848f;
  const float hv = (v > 0.f) ? SC * v : SC * AL * expm1f(v);  // SELU
  h2[(size_t)n * 64 + lane] = hv;
  const float p = wave_sum(hv * Wp[lane]);
  if (lane == 0) {
    const float di = rsqrtf((float)deg);
    q[n] = di * p;
    dinvArr[n] = di;
  }
}

// ---------------- GCN score ----------------
__global__ void score_kernel(const int* __restrict__ srcArr, const int* __restrict__ rowptr,
                             const int* __restrict__ eid, const float* __restrict__ q,
                             const float* __restrict__ dinvArr, const float* __restrict__ bp,
                             float* __restrict__ score) {
  const int n = blockIdx.x * 256 + threadIdx.x;
  if (n >= NN) return;
  const int base = rowptr[n], deg = rowptr[n + 1] - base;
  float s = 0.f;
  for (int i = 0; i < deg; ++i) {
    const int e = eid[base + i];
    const int src = (e < E0) ? srcArr[e] : (e - E0);
    s += q[src];
  }
  score[n] = bp[0] + dinvArr[n] * s;
}

// ---------------- per-graph top-K via in-LDS bitonic sort ----------------
__global__ __launch_bounds__(1024) void topk_kernel(const float* __restrict__ score,
                                                    int* __restrict__ perm) {
  constexpr int NPAD = 8192;
  __shared__ unsigned long long s[NPAD];  // 64 KiB
  const int b = blockIdx.x, tid = threadIdx.x;
  for (int i = tid; i < NPAD; i += 1024) {
    unsigned long long v = 0ull;
    if (i < N_PER) {
      const unsigned u = __float_as_uint(score[b * N_PER + i]);
      const unsigned okey = (u & 0x80000000u) ? ~u : (u | 0x80000000u);
      v = ((unsigned long long)okey << 32) | (unsigned)(N_PER - 1 - i);
    }
    s[i] = v;
  }
  __syncthreads();
  for (int k = 2; k <= NPAD; k <<= 1) {
    for (int j = k >> 1; j > 0; j >>= 1) {
      for (int t = tid; t < NPAD / 2; t += 1024) {
        const int i = ((t & ~(j - 1)) << 1) | (t & (j - 1));
        const int ixj = i | j;
        const bool up = ((i & k) == 0);
        const unsigned long long x = s[i], y = s[ixj];
        if (up ? (x < y) : (x > y)) { s[i] = y; s[ixj] = x; }
      }
      __syncthreads();
    }
  }
  for (int t = tid; t < KSEL; t += 1024) {
    const int idx = N_PER - 1 - (int)(s[t] & 0xFFFFFFFFull);
    perm[b * KSEL + t] = b * N_PER + idx;
  }
}

// ---------------- pooling: max || mean of h2*tanh(score) over selected ----------------
__global__ __launch_bounds__(256) void pool_kernel(const float* __restrict__ h2,
                                                   const float* __restrict__ score,
                                                   const int* __restrict__ perm,
                                                   float* __restrict__ pooled) {
  const int b = blockIdx.x;
  const int tid = threadIdx.x, wv = tid >> 6, lane = tid & 63;
  float mx = -FLT_MAX, sm = 0.f;
  for (int t = wv; t < KSEL; t += 4) {
    const int node = perm[b * KSEL + t];
    const float tv = tanhf(score[node]);
    const float x = h2[(size_t)node * DH + lane] * tv;
    mx = fmaxf(mx, x);
    sm += x;
  }
  __shared__ float smx[4][64], ssm[4][64];
  smx[wv][lane] = mx;
  ssm[wv][lane] = sm;
  __syncthreads();
  if (wv == 0) {
    const float M = fmaxf(fmaxf(smx[0][lane], smx[1][lane]), fmaxf(smx[2][lane], smx[3][lane]));
    const float S = ssm[0][lane] + ssm[1][lane] + ssm[2][lane] + ssm[3][lane];
    pooled[b * 128 + lane] = M;
    pooled[b * 128 + 64 + lane] = S / (float)KSEL;
  }
}

// ---------------- final linear + relu + log_softmax ----------------
__global__ __launch_bounds__(64) void final_kernel(const float* __restrict__ pooled,
                                                   const float* __restrict__ Wlin,
                                                   const float* __restrict__ blin,
                                                   float* __restrict__ out) {
  __shared__ float lg[NB][3];
  const int t = threadIdx.x;
  if (t < NB * 3) {
    const int b = t / 3, j = t % 3;
    float s = blin[j];
    for (int k = 0; k < 128; ++k) s = fmaf(pooled[b * 128 + k], Wlin[k * 3 + j], s);
    lg[b][j] = fmaxf(s, 0.f);
  }
  __syncthreads();
  if (t < NB) {
    const float a = lg[t][0], b2 = lg[t][1], c = lg[t][2];
    const float m = fmaxf(a, fmaxf(b2, c));
    const float lse = m + logf(expf(a - m) + expf(b2 - m) + expf(c - m));
    out[t * 3 + 0] = a - lse;
    out[t * 3 + 1] = b2 - lse;
    out[t * 3 + 2] = c - lse;
  }
}

// ---------------- launch ----------------
extern "C" void kernel_launch(void* const* d_in, const int* in_sizes, int n_in,
                              void* d_out, int out_size, void* d_ws, size_t ws_size,
                              hipStream_t stream) {
  (void)in_sizes; (void)n_in; (void)out_size; (void)ws_size;
  const float* x    = (const float*)d_in[0];
  const float* Wl1  = (const float*)d_in[1];
  const float* Wr1  = (const float*)d_in[2];
  const float* a1   = (const float*)d_in[3];
  const float* b1   = (const float*)d_in[4];
  const float* Wl2  = (const float*)d_in[5];
  const float* Wr2  = (const float*)d_in[6];
  const float* a2   = (const float*)d_in[7];
  const float* b2   = (const float*)d_in[8];
  const float* Wp   = (const float*)d_in[9];
  const float* bp   = (const float*)d_in[10];
  const float* Wlin = (const float*)d_in[11];
  const float* blin = (const float*)d_in[12];
  const int* ei     = (const int*)d_in[13];
  const int* srcArr = ei;
  const int* dstArr = ei + E0;
  float* out = (float*)d_out;

  // workspace layout (~209 MB, within round-0-proven budget)
  char* w = (char*)d_ws;
  size_t off = 0;
  auto alloc = [&](size_t bytes) -> void* {
    void* p = w + off;
    off = (off + bytes + 255) & ~(size_t)255;
    return p;
  };
  float* xl1   = (float*)alloc((size_t)MP * 512 * 4);  // later: xlr2 | h2
  float* xr1h1 = (float*)alloc((size_t)MP * 512 * 4);  // xr1 f32 -> h1 f32 in place
  short* BT1h = (short*)alloc((size_t)1024 * 1024 * 2);
  short* BT2h = (short*)alloc((size_t)128 * 512 * 2);
  int* deg    = (int*)alloc((size_t)NN * 4);
  int* rowptr = (int*)alloc((size_t)(NN + 1) * 4);
  int* cnt    = (int*)alloc((size_t)NN * 4);
  int* eid    = (int*)alloc((size_t)ET * 4);
  float* q      = (float*)alloc((size_t)NN * 4);
  float* dinv   = (float*)alloc((size_t)NN * 4);
  float* score  = (float*)alloc((size_t)NN * 4);
  int* perm     = (int*)alloc((size_t)NB * KSEL * 4);
  float* pooled = (float*)alloc((size_t)NB * 128 * 4);

  float* xlr2 = xl1;                                   // aliases xl1 (dead after node1)
  float* h2   = (float*)((char*)xl1 + (size_t)MP * 128 * 4);

  hipMemsetAsync(deg, 0, (size_t)NN * 4, stream);
  hipMemsetAsync(cnt, 0, (size_t)NN * 4, stream);

  deg_kernel<<<(ET + 255) / 256, 256, 0, stream>>>(dstArr, deg);
  scan_kernel<<<1, 1024, 0, stream>>>(deg, rowptr);
  fill_kernel<<<(ET + 255) / 256, 256, 0, stream>>>(dstArr, rowptr, cnt, eid);

  wconv1_kernel<<<(1024 * 1024) / 256, 256, 0, stream>>>(Wl1, Wr1, BT1h);
  wconv2_kernel<<<(128 * 512) / 256, 256, 0, stream>>>(Wl2, Wr2, BT2h);

  // layer-1 GEMM: [MP,1024] x [1024,1024] -> xl1 | xr1
  gemm_kernel<<<(MP / 128) * 8, 256, 0, stream>>>(
      x, DIN, BT1h, 1024, xl1, xr1h1, 512, 512, 1024, 8);
  node1_kernel<<<(NN + 3) / 4, 256, 0, stream>>>(xl1, xr1h1, srcArr, rowptr, eid, a1, b1);

  // layer-2 GEMM: [MP,512] x [512,128] -> xlr2 (A = h1 f32, in place of xr1)
  gemm_kernel<<<MP / 128, 256, 0, stream>>>(
      xr1h1, 512, BT2h, 512, xlr2, xlr2, 128, 128, 512, 1);
  node2_kernel<<<(NN + 3) / 4, 256, 0, stream>>>(xlr2, srcArr, rowptr, eid, a2, b2, Wp,
                                                 h2, q, dinv);

  score_kernel<<<(NN + 255) / 256, 256, 0, stream>>>(srcArr, rowptr, eid, q, dinv, bp, score);
  topk_kernel<<<NB, 1024, 0, stream>>>(score, perm);
  pool_kernel<<<NB, 256, 0, stream>>>(h2, score, perm, pooled);
  final_kernel<<<1, 64, 0, stream>>>(pooled, Wlin, blin, out);
}